// Round 18
// baseline (277.615 us; speedup 1.0000x reference)
//
#include <hip/hip_runtime.h>
#include <hip/hip_bf16.h>

// ScaledDotProductAttention: B=2,H=16,S=2048,D=64, fp32 in/out.
// Outputs: context [B,H,S,D] then attn [B,H,S,S], concatenated in d_out.
//
// R18: R17 with the compile fix — nontemporal stores go through the clang
// ext_vector type f32x4 (HIP's float4 struct is rejected by the builtin).
// NT hints on zero-reuse streams: mask loads (512MB read-once), attn
// stores (512MB write-once), ctx stores. Mechanism: keep L2 for the K/V
// images (512KB/bh, reused 32x; ~2MB hot per XCD under the swizzle).
// Everything else byte-identical to R16 (277.3us):
//  - pass 1: K quad-buffer, 2 tiles/barrier; mask->reg bitmask; setprio.
//  - pass 2: K/V dbuf, 1 tile/barrier; P per-wave swizzled LDS; setprio.
//  - no-max softmax (exact), exp2 domain, XCD swizzle, HW bf16 cvt,
//    prep kernel K/V bf16 swizzled images, LDS 40960B -> 4 blk/CU.

#define S_LEN 2048
#define D_DIM 64
#define NKT 32
#define QB 64

typedef __attribute__((ext_vector_type(8))) short bf16x8;
typedef __attribute__((ext_vector_type(4))) float f32x4;
typedef __attribute__((ext_vector_type(4))) unsigned short us4;

__device__ __forceinline__ unsigned short f2bf(float f) {
    return __builtin_bit_cast(unsigned short, __float2bfloat16(f));
}
__device__ __forceinline__ float bf2f(unsigned short b) {
    return __builtin_bit_cast(float, (unsigned)b << 16);
}

typedef const __attribute__((address_space(1))) void cg_void;
typedef __attribute__((address_space(3))) void lds_void;
__device__ __forceinline__ void gload16(const void* g, void* l) {
    __builtin_amdgcn_global_load_lds((cg_void*)g, (lds_void*)l, 16, 0, 0);
}

// ---------------- prep: K,V f32 -> swizzled bf16 tiles in ws ----------------
__global__ __launch_bounds__(256)
void sdpa_prep(const float* __restrict__ K, const float* __restrict__ V,
               unsigned short* __restrict__ Kimg, unsigned short* __restrict__ Vimg)
{
    const int blk = blockIdx.x;          // bh*32 + kt
    const int bh = blk >> 5, kt = blk & 31;
    const float* Kt = K + ((size_t)bh * S_LEN + kt * 64) * D_DIM;
    const float* Vt = V + ((size_t)bh * S_LEN + kt * 64) * D_DIM;
    unsigned char* Kd = (unsigned char*)(Kimg + (size_t)blk * 4096);
    unsigned char* Vd = (unsigned char*)(Vimg + (size_t)blk * 4096);
    const int tid = threadIdx.x;

    {
        const int srow = tid >> 4, c4 = tid & 15;
        #pragma unroll
        for (int i = 0; i < 4; ++i) {
            int row = srow + i * 16;
            float4 v = *(const float4*)(Kt + (size_t)row * D_DIM + c4 * 4);
            us4 b = { f2bf(v.x), f2bf(v.y), f2bf(v.z), f2bf(v.w) };
            *(us4*)(Kd + row * 128 + (((c4 >> 1) ^ (row & 7)) << 4) + (c4 & 1) * 8) = b;
        }
    }
    {
        const int d = tid & 63, kg = tid >> 6;
        #pragma unroll
        for (int kk = 0; kk < 4; ++kk) {
            int k4 = kg * 4 + kk;
            int k0 = k4 * 4;
            float v0 = Vt[(size_t)(k0 + 0) * D_DIM + d];
            float v1 = Vt[(size_t)(k0 + 1) * D_DIM + d];
            float v2 = Vt[(size_t)(k0 + 2) * D_DIM + d];
            float v3 = Vt[(size_t)(k0 + 3) * D_DIM + d];
            us4 b = { f2bf(v0), f2bf(v1), f2bf(v2), f2bf(v3) };
            *(us4*)(Vd + d * 128 + (((k4 >> 1) ^ (d & 7)) << 4) + (k4 & 1) * 8) = b;
        }
    }
}

// ------------------------------- main ---------------------------------------
__global__ __launch_bounds__(256, 4)
void sdpa_main(const float* __restrict__ Q,
               const int* __restrict__ M,
               const unsigned short* __restrict__ Kimg,
               const unsigned short* __restrict__ Vimg,
               float* __restrict__ ctx_out,
               float* __restrict__ attn_out)
{
    __shared__ __align__(16) unsigned char smem[40960];
    unsigned short* const sK0 = (unsigned short*)(smem);
    unsigned short* const sK1 = (unsigned short*)(smem + 8192);
    unsigned short* const sV0 = (unsigned short*)(smem + 16384);
    unsigned short* const sV1 = (unsigned short*)(smem + 24576);
    unsigned short* const sPB = (unsigned short*)(smem + 32768);
    unsigned short* const sQl = (unsigned short*)(smem + 32768);

    const int tid  = threadIdx.x;
    const int lane = tid & 63;
    const int w    = tid >> 6;
    const int lq   = lane & 15;
    const int h    = lane >> 4;
    const int l7   = lq & 7;

    int b   = blockIdx.x;
    int swz = (b & 7) * 128 + (b >> 3);
    int bh  = swz >> 5, qt = swz & 31;
    const int q0 = qt * QB;

    const float* Qh = Q + ((size_t)bh * S_LEN + q0) * D_DIM;
    const int*   Mh = M + (size_t)bh * S_LEN * S_LEN;
    const unsigned short* Kh = Kimg + (size_t)bh * NKT * 4096;
    const unsigned short* Vh = Vimg + (size_t)bh * NKT * 4096;
    float* Ah = attn_out + (size_t)bh * S_LEN * S_LEN;
    float* Ch = ctx_out  + (size_t)bh * S_LEN * D_DIM;

    const int kf0 = ((h)     ^ l7) << 3;
    const int kf1 = ((4 + h) ^ l7) << 3;

    const int* Mb = Mh + (size_t)(q0 + w * 16 + h * 4) * S_LEN + lq;

    unsigned bits[4][4];
    #pragma unroll
    for (int jt = 0; jt < 4; ++jt)
        #pragma unroll
        for (int r = 0; r < 4; ++r)
            bits[jt][r] = 0u;

    // ---- prologue: issue K(0),K(1); pack mask tiles 0,1; stage Q ----------
    #pragma unroll
    for (int tt = 0; tt < 2; ++tt)
        #pragma unroll
        for (int i = 0; i < 2; ++i)
            gload16((const unsigned char*)(Kh + (size_t)tt * 4096) + w * 2048 + i * 1024 + lane * 16,
                    smem + tt * 8192 + w * 2048 + i * 1024);
    __builtin_amdgcn_sched_barrier(0);

    #pragma unroll
    for (int tt = 0; tt < 2; ++tt)
        #pragma unroll
        for (int jt = 0; jt < 4; ++jt)
            #pragma unroll
            for (int r = 0; r < 4; ++r) {
                int m = __builtin_nontemporal_load(&Mb[(size_t)r * S_LEN + tt * 64 + jt * 16]);
                bits[jt][r] |= (m ? 1u : 0u) << tt;
            }

    const float SC = 0.18033688011112042f;   // 0.125 * log2(e)
    {
        const int srow = tid >> 4, c4 = tid & 15;
        #pragma unroll
        for (int i = 0; i < 4; ++i) {
            int row = srow + i * 16;
            float4 v = *(const float4*)(Qh + (size_t)row * D_DIM + c4 * 4);
            us4 bq = { f2bf(v.x * SC), f2bf(v.y * SC), f2bf(v.z * SC), f2bf(v.w * SC) };
            *(us4*)((unsigned char*)sQl + row * 128 + (((c4 >> 1) ^ (row & 7)) << 4) + (c4 & 1) * 8) = bq;
        }
    }
    __syncthreads();   // Q staged, K(0),K(1) resident

    bf16x8 aq0 = *(const bf16x8*)(&sQl[(w * 16 + lq) * 64 + kf0]);
    bf16x8 aq1 = *(const bf16x8*)(&sQl[(w * 16 + lq) * 64 + kf1]);

    // ================= pass 1: 16 steps x 2 tiles ===========================
    float lsum[4];
    #pragma unroll
    for (int r = 0; r < 4; ++r) lsum[r] = 0.f;

    for (int s = 0; s < 16; ++s) {
        const int kt0 = 2 * s;
        unsigned char* curp = smem + (s & 1) * 16384;
        unsigned char* nxtp = smem + ((s & 1) ^ 1) * 16384;
        const bool more = (s + 1 < 16);

        if (more) {
            #pragma unroll
            for (int tt = 0; tt < 2; ++tt)
                #pragma unroll
                for (int i = 0; i < 2; ++i)
                    gload16((const unsigned char*)(Kh + (size_t)(kt0 + 2 + tt) * 4096) + w * 2048 + i * 1024 + lane * 16,
                            nxtp + tt * 8192 + w * 2048 + i * 1024);
        }
        __builtin_amdgcn_sched_barrier(0);

        int mn[2][4][4];
        if (more) {
            #pragma unroll
            for (int tt = 0; tt < 2; ++tt)
                #pragma unroll
                for (int jt = 0; jt < 4; ++jt)
                    #pragma unroll
                    for (int r = 0; r < 4; ++r)
                        mn[tt][jt][r] = __builtin_nontemporal_load(
                            &Mb[(size_t)r * S_LEN + (kt0 + 2 + tt) * 64 + jt * 16]);
        }

        #pragma unroll
        for (int tt = 0; tt < 2; ++tt) {
            const unsigned short* kbuf = (const unsigned short*)(curp + tt * 8192);
            f32x4 acc[4];
            __builtin_amdgcn_s_setprio(1);
            #pragma unroll
            for (int jt = 0; jt < 4; ++jt) {
                acc[jt] = (f32x4){0.f, 0.f, 0.f, 0.f};
                const unsigned short* kb = kbuf + (jt * 16 + lq) * 64;
                bf16x8 b0 = *(const bf16x8*)(kb + kf0);
                bf16x8 b1 = *(const bf16x8*)(kb + kf1);
                acc[jt] = __builtin_amdgcn_mfma_f32_16x16x32_bf16(aq0, b0, acc[jt], 0, 0, 0);
                acc[jt] = __builtin_amdgcn_mfma_f32_16x16x32_bf16(aq1, b1, acc[jt], 0, 0, 0);
            }
            __builtin_amdgcn_s_setprio(0);
            #pragma unroll
            for (int r = 0; r < 4; ++r) {
                float e[4];
                #pragma unroll
                for (int jt = 0; jt < 4; ++jt) {
                    unsigned msk = (bits[jt][r] >> (kt0 + tt)) & 1u;
                    float ev = exp2f(acc[jt][r]);
                    e[jt] = msk ? 0.f : ev;
                }
                lsum[r] += (e[0] + e[1]) + (e[2] + e[3]);
            }
        }

        if (more) {
            #pragma unroll
            for (int tt = 0; tt < 2; ++tt)
                #pragma unroll
                for (int jt = 0; jt < 4; ++jt)
                    #pragma unroll
                    for (int r = 0; r < 4; ++r)
                        bits[jt][r] |= (mn[tt][jt][r] ? 1u : 0u) << (kt0 + 2 + tt);
        }
        __syncthreads();
    }

    // add-only butterfly; full 16-wide xor leaves the total in ALL lanes
    float myIL[4];
    #pragma unroll
    for (int r = 0; r < 4; ++r) {
        float li = lsum[r];
        #pragma unroll
        for (int off = 1; off < 16; off <<= 1)
            li += __shfl_xor(li, off);
        myIL[r] = (li > 0.f) ? (1.f / li) : 0.f;
    }

    // ---- pass-2 prologue: issue K(0), V(0) ----
    #pragma unroll
    for (int i = 0; i < 2; ++i) {
        gload16((const unsigned char*)Kh + w * 2048 + i * 1024 + lane * 16,
                (unsigned char*)sK0 + w * 2048 + i * 1024);
        gload16((const unsigned char*)Vh + w * 2048 + i * 1024 + lane * 16,
                (unsigned char*)sV0 + w * 2048 + i * 1024);
    }
    __syncthreads();

    // ================= pass 2: attn write + PV ==============================
    f32x4 ctxa[4];
    #pragma unroll
    for (int dt = 0; dt < 4; ++dt) ctxa[dt] = (f32x4){0.f, 0.f, 0.f, 0.f};

    unsigned short* const sPw = sPB + w * 1024;
    float* const Abase = Ah + (size_t)(q0 + w * 16) * S_LEN;

    auto step2 = [&](unsigned short* curK, unsigned short* curV,
                     unsigned short* nxtK, unsigned short* nxtV, int kt) {
        const int ktn = (kt + 1 < NKT) ? kt + 1 : kt;
        #pragma unroll
        for (int i = 0; i < 2; ++i) {
            gload16((const unsigned char*)(Kh + (size_t)ktn * 4096) + w * 2048 + i * 1024 + lane * 16,
                    (unsigned char*)nxtK + w * 2048 + i * 1024);
            gload16((const unsigned char*)(Vh + (size_t)ktn * 4096) + w * 2048 + i * 1024 + lane * 16,
                    (unsigned char*)nxtV + w * 2048 + i * 1024);
        }
        __builtin_amdgcn_sched_barrier(0);

        f32x4 acc[4];
        __builtin_amdgcn_s_setprio(1);
        #pragma unroll
        for (int jt = 0; jt < 4; ++jt) {
            acc[jt] = (f32x4){0.f, 0.f, 0.f, 0.f};
            const unsigned short* kb = curK + (jt * 16 + lq) * 64;
            bf16x8 b0 = *(const bf16x8*)(kb + kf0);
            bf16x8 b1 = *(const bf16x8*)(kb + kf1);
            acc[jt] = __builtin_amdgcn_mfma_f32_16x16x32_bf16(aq0, b0, acc[jt], 0, 0, 0);
            acc[jt] = __builtin_amdgcn_mfma_f32_16x16x32_bf16(aq1, b1, acc[jt], 0, 0, 0);
        }
        __builtin_amdgcn_s_setprio(0);

        // P -> per-wave swizzled LDS tile (bf16)
        #pragma unroll
        for (int jt = 0; jt < 4; ++jt)
            #pragma unroll
            for (int r = 0; r < 4; ++r) {
                bool msk = (bits[jt][r] >> kt) & 1u;
                float p = exp2f(acc[jt][r]) * myIL[r];
                p = msk ? 0.f : p;
                int row = h * 4 + r;
                sPw[row * 64 + ((((jt << 1) | (lq >> 3)) ^ (row & 7)) << 3) + l7] = f2bf(p);
            }
        asm volatile("s_waitcnt lgkmcnt(0)" ::: "memory");
        __builtin_amdgcn_sched_barrier(0);

        // coalesced attn write from sPw (nontemporal: write-once stream)
        float* Aw = Abase + kt * 64;
        #pragma unroll
        for (int it = 0; it < 4; ++it) {
            int row = it * 4 + h;
            us4 pb = *(const us4*)(&sPw[row * 64 + (((lq >> 1) ^ (row & 7)) << 3) + (lq & 1) * 4]);
            f32x4 pf = { bf2f(pb.x), bf2f(pb.y), bf2f(pb.z), bf2f(pb.w) };
            __builtin_nontemporal_store(pf, (f32x4*)(Aw + (size_t)row * S_LEN + lq * 4));
        }

        // PV
        bf16x8 pa0 = *(const bf16x8*)(&sPw[lq * 64 + ((h ^ l7) << 3)]);
        bf16x8 pa1 = *(const bf16x8*)(&sPw[lq * 64 + (((4 + h) ^ l7) << 3)]);
        __builtin_amdgcn_s_setprio(1);
        #pragma unroll
        for (int dt = 0; dt < 4; ++dt) {
            const unsigned short* vb = curV + (dt * 16 + lq) * 64;
            bf16x8 b0 = *(const bf16x8*)(vb + kf0);
            bf16x8 b1 = *(const bf16x8*)(vb + kf1);
            ctxa[dt] = __builtin_amdgcn_mfma_f32_16x16x32_bf16(pa0, b0, ctxa[dt], 0, 0, 0);
            ctxa[dt] = __builtin_amdgcn_mfma_f32_16x16x32_bf16(pa1, b1, ctxa[dt], 0, 0, 0);
        }
        __builtin_amdgcn_s_setprio(0);
        __syncthreads();
    };

    for (int kt = 0; kt < NKT; kt += 2) {
        step2(sK0, sV0, sK1, sV1, kt);
        step2(sK1, sV1, sK0, sV0, kt + 1);
    }

    float* Crow = Ch + (size_t)(q0 + w * 16 + h * 4) * D_DIM;
    #pragma unroll
    for (int dt = 0; dt < 4; ++dt)
        #pragma unroll
        for (int r = 0; r < 4; ++r)
            __builtin_nontemporal_store(ctxa[dt][r],
                Crow + (size_t)r * D_DIM + dt * 16 + lq);
}

extern "C" void kernel_launch(void* const* d_in, const int* in_sizes, int n_in,
                              void* d_out, int out_size, void* d_ws, size_t ws_size,
                              hipStream_t stream)
{
    const float* Q = (const float*)d_in[0];
    const float* K = (const float*)d_in[1];
    const float* V = (const float*)d_in[2];
    const int*   M = (const int*)d_in[3];

    float* ctx  = (float*)d_out;
    float* attn = ctx + (size_t)2 * 16 * S_LEN * D_DIM;

    const size_t imgElems = (size_t)32 * NKT * 4096;
    if (ws_size < 2 * imgElems * sizeof(unsigned short)) return; // need 16 MB
    unsigned short* Kimg = (unsigned short*)d_ws;
    unsigned short* Vimg = Kimg + imgElems;

    sdpa_prep<<<dim3(1024), 256, 0, stream>>>(K, V, Kimg, Vimg);
    sdpa_main<<<dim3(1024), 256, 0, stream>>>(Q, M, Kimg, Vimg, ctx, attn);
}

// Round 19
// 247.688 us; speedup vs baseline: 1.1208x; 1.1208x over previous
//
#include <hip/hip_runtime.h>
#include <hip/hip_bf16.h>

// ScaledDotProductAttention: B=2,H=16,S=2048,D=64, fp32 in/out.
// Outputs: context [B,H,S,D] then attn [B,H,S,S], concatenated in d_out.
//
// R19: mask stream moved OUT of the main kernel. New sdpa_mask kernel
// compresses the 512MB int32 mask into a 16MB bitword image at streaming
// BW (~6.5 TB/s, like fillBuffer), stored IN THE CTX OUTPUT REGION
// (identical 16.78MB size; each block reads exactly the slice it later
// overwrites with ctx -> no cross-block hazard, rewritten every call).
// Main pass 1 loses all per-step mask VMEM + prefetch rotation: bits[jt][r]
// = 16 one-time u32 loads. Everything else identical to R18/R16 (277us):
//  - pass 1: K quad-buffer, 2 tiles/barrier, setprio on MFMAs.
//  - pass 2: K/V dbuf, 1 tile/barrier; P per-wave swizzled LDS; setprio;
//    NT attn/ctx stores.
//  - no-max softmax (exact), exp2 domain, XCD swizzle, HW bf16 cvt,
//    prep kernel K/V bf16 swizzled images, LDS 40960B -> 4 blk/CU.

#define S_LEN 2048
#define D_DIM 64
#define NKT 32
#define QB 64

typedef __attribute__((ext_vector_type(8))) short bf16x8;
typedef __attribute__((ext_vector_type(4))) float f32x4;
typedef __attribute__((ext_vector_type(4))) unsigned short us4;

__device__ __forceinline__ unsigned short f2bf(float f) {
    return __builtin_bit_cast(unsigned short, __float2bfloat16(f));
}
__device__ __forceinline__ float bf2f(unsigned short b) {
    return __builtin_bit_cast(float, (unsigned)b << 16);
}

typedef const __attribute__((address_space(1))) void cg_void;
typedef __attribute__((address_space(3))) void lds_void;
__device__ __forceinline__ void gload16(const void* g, void* l) {
    __builtin_amdgcn_global_load_lds((cg_void*)g, (lds_void*)l, 16, 0, 0);
}

// ---------------- prep: K,V f32 -> swizzled bf16 tiles in ws ----------------
__global__ __launch_bounds__(256)
void sdpa_prep(const float* __restrict__ K, const float* __restrict__ V,
               unsigned short* __restrict__ Kimg, unsigned short* __restrict__ Vimg)
{
    const int blk = blockIdx.x;          // bh*32 + kt
    const int bh = blk >> 5, kt = blk & 31;
    const float* Kt = K + ((size_t)bh * S_LEN + kt * 64) * D_DIM;
    const float* Vt = V + ((size_t)bh * S_LEN + kt * 64) * D_DIM;
    unsigned char* Kd = (unsigned char*)(Kimg + (size_t)blk * 4096);
    unsigned char* Vd = (unsigned char*)(Vimg + (size_t)blk * 4096);
    const int tid = threadIdx.x;

    {
        const int srow = tid >> 4, c4 = tid & 15;
        #pragma unroll
        for (int i = 0; i < 4; ++i) {
            int row = srow + i * 16;
            float4 v = *(const float4*)(Kt + (size_t)row * D_DIM + c4 * 4);
            us4 b = { f2bf(v.x), f2bf(v.y), f2bf(v.z), f2bf(v.w) };
            *(us4*)(Kd + row * 128 + (((c4 >> 1) ^ (row & 7)) << 4) + (c4 & 1) * 8) = b;
        }
    }
    {
        const int d = tid & 63, kg = tid >> 6;
        #pragma unroll
        for (int kk = 0; kk < 4; ++kk) {
            int k4 = kg * 4 + kk;
            int k0 = k4 * 4;
            float v0 = Vt[(size_t)(k0 + 0) * D_DIM + d];
            float v1 = Vt[(size_t)(k0 + 1) * D_DIM + d];
            float v2 = Vt[(size_t)(k0 + 2) * D_DIM + d];
            float v3 = Vt[(size_t)(k0 + 3) * D_DIM + d];
            us4 b = { f2bf(v0), f2bf(v1), f2bf(v2), f2bf(v3) };
            *(us4*)(Vd + d * 128 + (((k4 >> 1) ^ (d & 7)) << 4) + (k4 & 1) * 8) = b;
        }
    }
}

// -------- mask compress: int32 [32][2048][2048] -> u32 bitwords -------------
// Bimg[(bh*2048 + q)*64 + c] bit kt = (mask[bh][q][kt*64 + c] != 0).
// Bimg aliases the ctx output region (same 16.78MB; main reads its slice
// in its prologue and overwrites it with ctx in its epilogue).
__global__ __launch_bounds__(256)
void sdpa_mask(const int* __restrict__ M, unsigned* __restrict__ Bimg)
{
    const int blk = blockIdx.x;           // bh*128 + qg
    const int bh = blk >> 7, qg = blk & 127;
    const int tid = threadIdx.x;
    const int wv = tid >> 6, lane = tid & 63;
    const int q = qg * 16 + wv * 4;       // this wave: rows q..q+3
    const int* Mq = M + ((size_t)bh * S_LEN + q) * S_LEN;
    unsigned* Bq = Bimg + ((size_t)bh * S_LEN + q) * 64;

    #pragma unroll
    for (int r = 0; r < 4; ++r) {
        unsigned word = 0;
        #pragma unroll 8
        for (int kt = 0; kt < 32; ++kt) {
            int m = __builtin_nontemporal_load(&Mq[(size_t)r * S_LEN + kt * 64 + lane]);
            word |= (m ? 1u : 0u) << kt;
        }
        Bq[r * 64 + lane] = word;
    }
}

// ------------------------------- main ---------------------------------------
__global__ __launch_bounds__(256, 4)
void sdpa_main(const float* __restrict__ Q,
               const unsigned short* __restrict__ Kimg,
               const unsigned short* __restrict__ Vimg,
               float* __restrict__ ctx_out,
               float* __restrict__ attn_out)
{
    __shared__ __align__(16) unsigned char smem[40960];
    unsigned short* const sK0 = (unsigned short*)(smem);
    unsigned short* const sK1 = (unsigned short*)(smem + 8192);
    unsigned short* const sV0 = (unsigned short*)(smem + 16384);
    unsigned short* const sV1 = (unsigned short*)(smem + 24576);
    unsigned short* const sPB = (unsigned short*)(smem + 32768);
    unsigned short* const sQl = (unsigned short*)(smem + 32768);

    const int tid  = threadIdx.x;
    const int lane = tid & 63;
    const int w    = tid >> 6;
    const int lq   = lane & 15;
    const int h    = lane >> 4;
    const int l7   = lq & 7;

    int b   = blockIdx.x;
    int swz = (b & 7) * 128 + (b >> 3);
    int bh  = swz >> 5, qt = swz & 31;
    const int q0 = qt * QB;

    const float* Qh = Q + ((size_t)bh * S_LEN + q0) * D_DIM;
    const unsigned short* Kh = Kimg + (size_t)bh * NKT * 4096;
    const unsigned short* Vh = Vimg + (size_t)bh * NKT * 4096;
    float* Ah = attn_out + (size_t)bh * S_LEN * S_LEN;
    float* Ch = ctx_out  + (size_t)bh * S_LEN * D_DIM;

    const int kf0 = ((h)     ^ l7) << 3;
    const int kf1 = ((4 + h) ^ l7) << 3;

    // ---- load this thread's mask bitwords (from the ctx-region bitmask) ----
    const unsigned* Bb = (const unsigned*)ctx_out
                       + ((size_t)bh * S_LEN + q0 + w * 16 + h * 4) * 64;
    unsigned bits[4][4];
    #pragma unroll
    for (int r = 0; r < 4; ++r)
        #pragma unroll
        for (int jt = 0; jt < 4; ++jt)
            bits[jt][r] = Bb[r * 64 + jt * 16 + lq];

    // ---- prologue: issue K(0),K(1); stage Q ----
    #pragma unroll
    for (int tt = 0; tt < 2; ++tt)
        #pragma unroll
        for (int i = 0; i < 2; ++i)
            gload16((const unsigned char*)(Kh + (size_t)tt * 4096) + w * 2048 + i * 1024 + lane * 16,
                    smem + tt * 8192 + w * 2048 + i * 1024);
    __builtin_amdgcn_sched_barrier(0);

    const float SC = 0.18033688011112042f;   // 0.125 * log2(e)
    {
        const int srow = tid >> 4, c4 = tid & 15;
        #pragma unroll
        for (int i = 0; i < 4; ++i) {
            int row = srow + i * 16;
            float4 v = *(const float4*)(Qh + (size_t)row * D_DIM + c4 * 4);
            us4 bq = { f2bf(v.x * SC), f2bf(v.y * SC), f2bf(v.z * SC), f2bf(v.w * SC) };
            *(us4*)((unsigned char*)sQl + row * 128 + (((c4 >> 1) ^ (row & 7)) << 4) + (c4 & 1) * 8) = bq;
        }
    }
    __syncthreads();   // Q staged, K(0),K(1) resident

    bf16x8 aq0 = *(const bf16x8*)(&sQl[(w * 16 + lq) * 64 + kf0]);
    bf16x8 aq1 = *(const bf16x8*)(&sQl[(w * 16 + lq) * 64 + kf1]);

    // ================= pass 1: 16 steps x 2 tiles ===========================
    float lsum[4];
    #pragma unroll
    for (int r = 0; r < 4; ++r) lsum[r] = 0.f;

    for (int s = 0; s < 16; ++s) {
        const int kt0 = 2 * s;
        unsigned char* curp = smem + (s & 1) * 16384;
        unsigned char* nxtp = smem + ((s & 1) ^ 1) * 16384;
        const bool more = (s + 1 < 16);

        if (more) {
            #pragma unroll
            for (int tt = 0; tt < 2; ++tt)
                #pragma unroll
                for (int i = 0; i < 2; ++i)
                    gload16((const unsigned char*)(Kh + (size_t)(kt0 + 2 + tt) * 4096) + w * 2048 + i * 1024 + lane * 16,
                            nxtp + tt * 8192 + w * 2048 + i * 1024);
        }
        __builtin_amdgcn_sched_barrier(0);

        #pragma unroll
        for (int tt = 0; tt < 2; ++tt) {
            const unsigned short* kbuf = (const unsigned short*)(curp + tt * 8192);
            f32x4 acc[4];
            __builtin_amdgcn_s_setprio(1);
            #pragma unroll
            for (int jt = 0; jt < 4; ++jt) {
                acc[jt] = (f32x4){0.f, 0.f, 0.f, 0.f};
                const unsigned short* kb = kbuf + (jt * 16 + lq) * 64;
                bf16x8 b0 = *(const bf16x8*)(kb + kf0);
                bf16x8 b1 = *(const bf16x8*)(kb + kf1);
                acc[jt] = __builtin_amdgcn_mfma_f32_16x16x32_bf16(aq0, b0, acc[jt], 0, 0, 0);
                acc[jt] = __builtin_amdgcn_mfma_f32_16x16x32_bf16(aq1, b1, acc[jt], 0, 0, 0);
            }
            __builtin_amdgcn_s_setprio(0);
            #pragma unroll
            for (int r = 0; r < 4; ++r) {
                float e[4];
                #pragma unroll
                for (int jt = 0; jt < 4; ++jt) {
                    unsigned msk = (bits[jt][r] >> (kt0 + tt)) & 1u;
                    float ev = exp2f(acc[jt][r]);
                    e[jt] = msk ? 0.f : ev;
                }
                lsum[r] += (e[0] + e[1]) + (e[2] + e[3]);
            }
        }
        __syncthreads();
    }

    // add-only butterfly; full 16-wide xor leaves the total in ALL lanes
    float myIL[4];
    #pragma unroll
    for (int r = 0; r < 4; ++r) {
        float li = lsum[r];
        #pragma unroll
        for (int off = 1; off < 16; off <<= 1)
            li += __shfl_xor(li, off);
        myIL[r] = (li > 0.f) ? (1.f / li) : 0.f;
    }

    // ---- pass-2 prologue: issue K(0), V(0) ----
    #pragma unroll
    for (int i = 0; i < 2; ++i) {
        gload16((const unsigned char*)Kh + w * 2048 + i * 1024 + lane * 16,
                (unsigned char*)sK0 + w * 2048 + i * 1024);
        gload16((const unsigned char*)Vh + w * 2048 + i * 1024 + lane * 16,
                (unsigned char*)sV0 + w * 2048 + i * 1024);
    }
    __syncthreads();

    // ================= pass 2: attn write + PV ==============================
    f32x4 ctxa[4];
    #pragma unroll
    for (int dt = 0; dt < 4; ++dt) ctxa[dt] = (f32x4){0.f, 0.f, 0.f, 0.f};

    unsigned short* const sPw = sPB + w * 1024;
    float* const Abase = Ah + (size_t)(q0 + w * 16) * S_LEN;

    auto step2 = [&](unsigned short* curK, unsigned short* curV,
                     unsigned short* nxtK, unsigned short* nxtV, int kt) {
        const int ktn = (kt + 1 < NKT) ? kt + 1 : kt;
        #pragma unroll
        for (int i = 0; i < 2; ++i) {
            gload16((const unsigned char*)(Kh + (size_t)ktn * 4096) + w * 2048 + i * 1024 + lane * 16,
                    (unsigned char*)nxtK + w * 2048 + i * 1024);
            gload16((const unsigned char*)(Vh + (size_t)ktn * 4096) + w * 2048 + i * 1024 + lane * 16,
                    (unsigned char*)nxtV + w * 2048 + i * 1024);
        }
        __builtin_amdgcn_sched_barrier(0);

        f32x4 acc[4];
        __builtin_amdgcn_s_setprio(1);
        #pragma unroll
        for (int jt = 0; jt < 4; ++jt) {
            acc[jt] = (f32x4){0.f, 0.f, 0.f, 0.f};
            const unsigned short* kb = curK + (jt * 16 + lq) * 64;
            bf16x8 b0 = *(const bf16x8*)(kb + kf0);
            bf16x8 b1 = *(const bf16x8*)(kb + kf1);
            acc[jt] = __builtin_amdgcn_mfma_f32_16x16x32_bf16(aq0, b0, acc[jt], 0, 0, 0);
            acc[jt] = __builtin_amdgcn_mfma_f32_16x16x32_bf16(aq1, b1, acc[jt], 0, 0, 0);
        }
        __builtin_amdgcn_s_setprio(0);

        // P -> per-wave swizzled LDS tile (bf16)
        #pragma unroll
        for (int jt = 0; jt < 4; ++jt)
            #pragma unroll
            for (int r = 0; r < 4; ++r) {
                bool msk = (bits[jt][r] >> kt) & 1u;
                float p = exp2f(acc[jt][r]) * myIL[r];
                p = msk ? 0.f : p;
                int row = h * 4 + r;
                sPw[row * 64 + ((((jt << 1) | (lq >> 3)) ^ (row & 7)) << 3) + l7] = f2bf(p);
            }
        asm volatile("s_waitcnt lgkmcnt(0)" ::: "memory");
        __builtin_amdgcn_sched_barrier(0);

        // coalesced attn write from sPw (nontemporal: write-once stream)
        float* Aw = Abase + kt * 64;
        #pragma unroll
        for (int it = 0; it < 4; ++it) {
            int row = it * 4 + h;
            us4 pb = *(const us4*)(&sPw[row * 64 + (((lq >> 1) ^ (row & 7)) << 3) + (lq & 1) * 4]);
            f32x4 pf = { bf2f(pb.x), bf2f(pb.y), bf2f(pb.z), bf2f(pb.w) };
            __builtin_nontemporal_store(pf, (f32x4*)(Aw + (size_t)row * S_LEN + lq * 4));
        }

        // PV
        bf16x8 pa0 = *(const bf16x8*)(&sPw[lq * 64 + ((h ^ l7) << 3)]);
        bf16x8 pa1 = *(const bf16x8*)(&sPw[lq * 64 + (((4 + h) ^ l7) << 3)]);
        __builtin_amdgcn_s_setprio(1);
        #pragma unroll
        for (int dt = 0; dt < 4; ++dt) {
            const unsigned short* vb = curV + (dt * 16 + lq) * 64;
            bf16x8 b0 = *(const bf16x8*)(vb + kf0);
            bf16x8 b1 = *(const bf16x8*)(vb + kf1);
            ctxa[dt] = __builtin_amdgcn_mfma_f32_16x16x32_bf16(pa0, b0, ctxa[dt], 0, 0, 0);
            ctxa[dt] = __builtin_amdgcn_mfma_f32_16x16x32_bf16(pa1, b1, ctxa[dt], 0, 0, 0);
        }
        __builtin_amdgcn_s_setprio(0);
        __syncthreads();
    };

    for (int kt = 0; kt < NKT; kt += 2) {
        step2(sK0, sV0, sK1, sV1, kt);
        step2(sK1, sV1, sK0, sV0, kt + 1);
    }

    float* Crow = Ch + (size_t)(q0 + w * 16 + h * 4) * D_DIM;
    #pragma unroll
    for (int dt = 0; dt < 4; ++dt)
        #pragma unroll
        for (int r = 0; r < 4; ++r)
            __builtin_nontemporal_store(ctxa[dt][r],
                Crow + (size_t)r * D_DIM + dt * 16 + lq);
}

extern "C" void kernel_launch(void* const* d_in, const int* in_sizes, int n_in,
                              void* d_out, int out_size, void* d_ws, size_t ws_size,
                              hipStream_t stream)
{
    const float* Q = (const float*)d_in[0];
    const float* K = (const float*)d_in[1];
    const float* V = (const float*)d_in[2];
    const int*   M = (const int*)d_in[3];

    float* ctx  = (float*)d_out;
    float* attn = ctx + (size_t)2 * 16 * S_LEN * D_DIM;

    const size_t imgElems = (size_t)32 * NKT * 4096;
    if (ws_size < 2 * imgElems * sizeof(unsigned short)) return; // need 16 MB
    unsigned short* Kimg = (unsigned short*)d_ws;
    unsigned short* Vimg = Kimg + imgElems;

    sdpa_prep<<<dim3(1024), 256, 0, stream>>>(K, V, Kimg, Vimg);
    sdpa_mask<<<dim3(4096), 256, 0, stream>>>(M, (unsigned*)ctx);
    sdpa_main<<<dim3(1024), 256, 0, stream>>>(Q, Kimg, Vimg, ctx, attn);
}